// Round 2
// baseline (1797.723 us; speedup 1.0000x reference)
//
#include <hip/hip_runtime.h>
#include <stdint.h>
#include <math.h>

typedef unsigned short u16;
typedef __attribute__((ext_vector_type(8))) short bf16x8;   // 8 bf16 (4 VGPRs)
typedef __attribute__((ext_vector_type(4))) float f32x4;    // MFMA accumulator

#define HS   1024
#define NEXP 8
#define FFN  4096

// ---------- small helpers ----------
__device__ __forceinline__ u16 f2b(float f) {              // fp32 -> bf16, RNE
  uint32_t u = __builtin_bit_cast(uint32_t, f);
  u = (u + 0x7fffu + ((u >> 16) & 1u)) >> 16;
  return (u16)u;
}
__device__ __forceinline__ float gelu_tanh(float x) {      // JAX approximate=True
  float z = 0.7978845608028654f * (x + 0.044715f * x * x * x);
  float e = __expf(2.0f * z);
  return 0.5f * x * (1.0f + (1.0f - 2.0f / (e + 1.0f)));
}
__device__ __forceinline__ void gload_lds16(const void* g, void* l) {
  // async global->LDS, 16B/lane; global addr is per-lane (gather OK),
  // LDS dst must be wave-uniform base + lane*16 (m104) — our layout is.
  __builtin_amdgcn_global_load_lds(
      (__attribute__((address_space(1))) void*)(void*)g,
      (__attribute__((address_space(3))) void*)l, 16, 0, 0);
}

// ---------- x: fp32 -> bf16, token order ----------
__global__ __launch_bounds__(256) void convert_bf16(const float* __restrict__ in,
                                                    u16* __restrict__ out) {
  const int i = (blockIdx.x * 256 + threadIdx.x) * 4;
  float4 v = *(const float4*)(in + i);
  ushort4 o;
  o.x = f2b(v.x); o.y = f2b(v.y); o.z = f2b(v.z); o.w = f2b(v.w);
  *(ushort4*)(out + i) = o;
}

// ---------- transpose + convert:  in [K][N] f32 -> out [N][K] bf16 ----------
__global__ __launch_bounds__(256) void transpose_convert(const float* __restrict__ in,
                                                         u16* __restrict__ out,
                                                         int K, int N) {
  __shared__ u16 tile[32][33];
  const int k0 = blockIdx.y * 32, n0 = blockIdx.x * 32;
  const int tx = threadIdx.x & 31, ty = threadIdx.x >> 5;   // 32 x 8
#pragma unroll
  for (int i = 0; i < 4; ++i)
    tile[ty + i * 8][tx] = f2b(in[(size_t)(k0 + ty + i * 8) * N + n0 + tx]);
  __syncthreads();
#pragma unroll
  for (int i = 0; i < 4; ++i)
    out[(size_t)(n0 + ty + i * 8) * K + k0 + tx] = tile[tx][ty + i * 8];
}

// ---------- router: fp64 logits, softmax, top-2 (tie -> lower index) ----------
__global__ __launch_bounds__(256) void router_kernel(const float* __restrict__ x,
                                                     const float* __restrict__ wr,
                                                     int T, int* __restrict__ experts,
                                                     float* __restrict__ weights) {
  const int wave = threadIdx.x >> 6, lane = threadIdx.x & 63;
  const int t = blockIdx.x * 4 + wave;
  if (t >= T) return;
  const float* xr = x + (size_t)t * HS;
  double acc[8] = {0, 0, 0, 0, 0, 0, 0, 0};
#pragma unroll
  for (int i = 0; i < HS / 64; ++i) {
    const int hrow = i * 64 + lane;
    double xv = (double)xr[hrow];
    float4 w0 = *(const float4*)(wr + hrow * 8);
    float4 w1 = *(const float4*)(wr + hrow * 8 + 4);
    acc[0] += xv * (double)w0.x; acc[1] += xv * (double)w0.y;
    acc[2] += xv * (double)w0.z; acc[3] += xv * (double)w0.w;
    acc[4] += xv * (double)w1.x; acc[5] += xv * (double)w1.y;
    acc[6] += xv * (double)w1.z; acc[7] += xv * (double)w1.w;
  }
#pragma unroll
  for (int e = 0; e < 8; ++e) {
    double v = acc[e];
#pragma unroll
    for (int off = 32; off > 0; off >>= 1) v += __shfl_xor(v, off, 64);
    acc[e] = v;
  }
  if (lane == 0) {
    double m = acc[0];
#pragma unroll
    for (int e = 1; e < 8; ++e) m = acc[e] > m ? acc[e] : m;
    double s[8], sum = 0.0;
#pragma unroll
    for (int e = 0; e < 8; ++e) { s[e] = exp(acc[e] - m); sum += s[e]; }
    double inv = 1.0 / sum;
    int e1 = 0; double l1 = acc[0];
#pragma unroll
    for (int e = 1; e < 8; ++e) if (acc[e] > l1) { l1 = acc[e]; e1 = e; }
    int e2 = -1; double l2 = -1e300;
#pragma unroll
    for (int e = 0; e < 8; ++e) if (e != e1 && acc[e] > l2) { l2 = acc[e]; e2 = e; }
    experts[2 * t] = e1;  experts[2 * t + 1] = e2;
    weights[2 * t] = (float)(s[e1] * inv);
    weights[2 * t + 1] = (float)(s[e2] * inv);
  }
}

// ---------- per-wave expert histogram + in-wave stable rank ----------
__global__ __launch_bounds__(256) void hist_kernel(const int* __restrict__ experts,
                                                   int* __restrict__ hist,
                                                   unsigned char* __restrict__ lrank) {
  const int n = blockIdx.x * 256 + threadIdx.x;
  const int lane = threadIdx.x & 63;
  const int wid = n >> 6;
  const int e = experts[n];
  int rank = 0;
#pragma unroll
  for (int ev = 0; ev < 8; ++ev) {
    unsigned long long m = __ballot(e == ev);
    if (lane == ev) hist[wid * 8 + ev] = __popcll(m);
    if (e == ev) rank = __popcll(m & ((1ull << lane) - 1ull));
  }
  lrank[n] = (unsigned char)rank;
}

// ---------- single-block scan: chunk-EXCLUSIVE prefix per expert ----------
// (within-expert offset only — reference: offsets = arange(N) - starts[bin_ids])
__global__ __launch_bounds__(512) void scan_kernel(const int* __restrict__ hist,
                                                   int* __restrict__ chunkBase) {
  __shared__ int s[512];
  const int tid = threadIdx.x;     // 512 == nChunks
  for (int e = 0; e < 8; ++e) {
    int v = hist[tid * 8 + e];
    s[tid] = v;
    __syncthreads();
    for (int off = 1; off < 512; off <<= 1) {
      int add = (tid >= off) ? s[tid - off] : 0;
      __syncthreads();
      s[tid] += add;
      __syncthreads();
    }
    chunkBase[tid * 8 + e] = s[tid] - v;   // exclusive, no expert-start
    __syncthreads();
  }
}

// ---------- slot map: init to empty, then fill (token index + combine weight) ----------
__global__ __launch_bounds__(256) void slot_init(int* __restrict__ rowtok,
                                                 float* __restrict__ roww) {
  const int i = blockIdx.x * 256 + threadIdx.x;
  rowtok[i] = -1;
  roww[i] = 0.0f;
}
__global__ __launch_bounds__(256) void slot_fill(const int* __restrict__ experts,
                                                 const unsigned char* __restrict__ lrank,
                                                 const int* __restrict__ chunkBase,
                                                 const float* __restrict__ weights,
                                                 int capacity, int* __restrict__ rowtok,
                                                 float* __restrict__ roww) {
  const int n = blockIdx.x * 256 + threadIdx.x;
  const int e = experts[n];
  const int off = chunkBase[(n >> 6) * 8 + e] + (int)lrank[n];
  if (off < capacity) {
    rowtok[e * capacity + off] = n >> 1;     // src token
    roww[e * capacity + off] = weights[n];
  }
}

// ---------- bias broadcast into out ----------
__global__ __launch_bounds__(256) void bias_init(const float* __restrict__ bias,
                                                 float* __restrict__ out) {
  const int c = threadIdx.x * 4;
  *(float4*)(out + (size_t)blockIdx.x * HS + c) = *(const float4*)(bias + c);
}

// ---------- m97-style bf16 GEMM for one expert ----------
// GATHER_A: A-rows gathered from xbf via rowtok (empty slot -> row 0, garbage ok)
// SCATTER:  epilogue atomically adds w*acc into out[token] (fp32); else writes
//           bf16 tile to Cout (with optional GELU).
// A: [M][K] or gathered [*][K]; Bt: [Nn][K]; all bf16 row-major.
template <bool GELU, bool GATHER_A, bool SCATTER>
__global__ __launch_bounds__(256) void gemm_moe(const u16* __restrict__ A,
                                                const u16* __restrict__ Bt,
                                                u16* __restrict__ Cout,
                                                float* __restrict__ out,
                                                const int* __restrict__ rowtok,
                                                const float* __restrict__ roww,
                                                int M, int Nn, int K) {
  const int bm = blockIdx.y, bn = blockIdx.x;
  const u16* Bb = Bt + (size_t)bn * 128 * K;
  __shared__ u16 As[128 * 32];   // [m][k]
  __shared__ u16 Bs[128 * 32];   // [n][k]
  const int tid = threadIdx.x;
  const int lane = tid & 63, wave = tid >> 6;
  const int wm = (wave >> 1) * 64, wn = (wave & 1) * 64;   // 2x2 waves over 128x128
  const int lrow = lane & 15, quad = lane >> 4;

  f32x4 acc[4][4] = {};

  const int srow = tid >> 2;                // staging row 0..63 (+64 second call)
  const int skoff = (tid & 3) * 8;          // k element offset
  u16* lA = As + tid * 8;                   // byte offset tid*16: lane-contig per wave
  u16* lB = Bs + tid * 8;

  const u16 *ga0, *ga1;
  if (GATHER_A) {
    int t0 = rowtok[bm * 128 + srow];      if (t0 < 0) t0 = 0;
    int t1 = rowtok[bm * 128 + srow + 64]; if (t1 < 0) t1 = 0;
    ga0 = A + (size_t)t0 * K + skoff;
    ga1 = A + (size_t)t1 * K + skoff;
  } else {
    ga0 = A + (size_t)(bm * 128 + srow) * K + skoff;
    ga1 = ga0 + (size_t)64 * K;
  }
  const u16* gb0 = Bb + (size_t)srow * K + skoff;
  const u16* gb1 = gb0 + (size_t)64 * K;

  for (int k0 = 0; k0 < K; k0 += 32) {
    gload_lds16(ga0 + k0, lA);
    gload_lds16(ga1 + k0, lA + 2048);
    gload_lds16(gb0 + k0, lB);
    gload_lds16(gb1 + k0, lB + 2048);
    __syncthreads();
    bf16x8 af[4], bfr[4];
#pragma unroll
    for (int i = 0; i < 4; ++i) {
      af[i]  = *(const bf16x8*)(As + (wm + i * 16 + lrow) * 32 + quad * 8);
      bfr[i] = *(const bf16x8*)(Bs + (wn + i * 16 + lrow) * 32 + quad * 8);
    }
#pragma unroll
    for (int i = 0; i < 4; ++i)
#pragma unroll
      for (int j = 0; j < 4; ++j)
        acc[i][j] = __builtin_amdgcn_mfma_f32_16x16x32_bf16(af[i], bfr[j], acc[i][j], 0, 0, 0);
    __syncthreads();
  }

  // C/D layout: col=lane&15, row=quad*4+reg (m89-verified)
  if (!SCATTER) {
    u16* Cb = Cout + (size_t)(bm * 128 + wm) * Nn + bn * 128 + wn;
#pragma unroll
    for (int i = 0; i < 4; ++i)
#pragma unroll
      for (int j = 0; j < 4; ++j)
#pragma unroll
        for (int r = 0; r < 4; ++r) {
          float v = acc[i][j][r];
          if (GELU) v = gelu_tanh(v);
          Cb[(size_t)(i * 16 + quad * 4 + r) * Nn + j * 16 + lrow] = f2b(v);
        }
  } else {
#pragma unroll
    for (int i = 0; i < 4; ++i)
#pragma unroll
      for (int r = 0; r < 4; ++r) {
        const int row = bm * 128 + wm + i * 16 + quad * 4 + r;
        const int tok = rowtok[row];
        const float w = roww[row];
        if (tok >= 0) {
          float* op = out + (size_t)tok * HS + bn * 128 + wn + lrow;
#pragma unroll
          for (int j = 0; j < 4; ++j)
            atomicAdd(op + j * 16, w * acc[i][j][r]);
        }
      }
  }
}

extern "C" void kernel_launch(void* const* d_in, const int* in_sizes, int n_in,
                              void* d_out, int out_size, void* d_ws, size_t ws_size,
                              hipStream_t stream) {
  const float* x    = (const float*)d_in[0];
  const float* wr   = (const float*)d_in[1];
  const float* w1   = (const float*)d_in[2];
  const float* w2   = (const float*)d_in[3];
  const float* bias = (const float*)d_in[4];
  float* out = (float*)d_out;

  const int T = in_sizes[0] / HS;          // 16384
  const int N = T * 2;                     // 32768 assignments
  const int capacity = N / NEXP;           // 4096
  const int nChunks = N / 64;              // 512

  // ---- workspace layout (~80.6 MB) ----
  char* ws = (char*)d_ws;
  int* experts = (int*)ws;                   ws += (size_t)N * 4;
  float* weights = (float*)ws;               ws += (size_t)N * 4;
  unsigned char* lrank = (unsigned char*)ws; ws += (size_t)N;
  int* hist = (int*)ws;                      ws += (size_t)nChunks * 8 * 4;
  int* chunkBase = (int*)ws;                 ws += (size_t)nChunks * 8 * 4;
  int* rowtok = (int*)ws;                    ws += (size_t)NEXP * capacity * 4;
  float* roww = (float*)ws;                  ws += (size_t)NEXP * capacity * 4;
  ws = (char*)(((uintptr_t)ws + 255) & ~(uintptr_t)255);
  u16* xbf = (u16*)ws;  ws += (size_t)T * HS * 2;          // 32 MB token-order bf16 x
  u16* w1t = (u16*)ws;  ws += (size_t)FFN * HS * 2;        // 8 MB  [ffn][hs] (1 expert)
  u16* w2t = (u16*)ws;  ws += (size_t)HS * FFN * 2;        // 8 MB  [hs][ffn] (1 expert)
  u16* h   = (u16*)ws;  ws += (size_t)capacity * FFN * 2;  // 32 MB [cap][ffn] (1 expert)
  if ((size_t)(ws - (char*)d_ws) > ws_size) return;  // workspace too small

  // token-order bf16 conversion of x
  convert_bf16<<<T * HS / 1024, 256, 0, stream>>>(x, xbf);
  // router + stable binning
  router_kernel<<<T / 4, 256, 0, stream>>>(x, wr, T, experts, weights);
  hist_kernel<<<N / 256, 256, 0, stream>>>(experts, hist, lrank);
  scan_kernel<<<1, 512, 0, stream>>>(hist, chunkBase);
  slot_init<<<NEXP * capacity / 256, 256, 0, stream>>>(rowtok, roww);
  slot_fill<<<N / 256, 256, 0, stream>>>(experts, lrank, chunkBase, weights,
                                         capacity, rowtok, roww);
  // out = bias (broadcast); GEMM2 scatter-adds on top
  bias_init<<<T, 256, 0, stream>>>(bias, out);

  // per-expert grouped MLP (stream-serialized; buffers reused)
  for (int e = 0; e < NEXP; ++e) {
    const float* w1_e = w1 + (size_t)e * HS * FFN;
    const float* w2_e = w2 + (size_t)e * FFN * HS;
    const int* rowtok_e = rowtok + e * capacity;
    const float* roww_e = roww + e * capacity;
    transpose_convert<<<dim3(FFN / 32, HS / 32), 256, 0, stream>>>(w1_e, w1t, HS, FFN);
    transpose_convert<<<dim3(HS / 32, FFN / 32), 256, 0, stream>>>(w2_e, w2t, FFN, HS);
    gemm_moe<true, true, false><<<dim3(FFN / 128, capacity / 128), 256, 0, stream>>>(
        xbf, w1t, h, nullptr, rowtok_e, roww_e, capacity, FFN, HS);
    gemm_moe<false, false, true><<<dim3(HS / 128, capacity / 128), 256, 0, stream>>>(
        h, w2t, nullptr, out, rowtok_e, roww_e, capacity, HS, FFN);
  }
}

// Round 3
// 1315.421 us; speedup vs baseline: 1.3667x; 1.3667x over previous
//
#include <hip/hip_runtime.h>
#include <stdint.h>
#include <math.h>

typedef unsigned short u16;
typedef __attribute__((ext_vector_type(8))) short bf16x8;   // 8 bf16 (4 VGPRs)
typedef __attribute__((ext_vector_type(4))) float f32x4;    // MFMA accumulator

#define HS   1024
#define NEXP 8
#define FFN  4096

// ---------- small helpers ----------
__device__ __forceinline__ u16 f2b(float f) {              // fp32 -> bf16, RNE
  uint32_t u = __builtin_bit_cast(uint32_t, f);
  u = (u + 0x7fffu + ((u >> 16) & 1u)) >> 16;
  return (u16)u;
}
__device__ __forceinline__ float gelu_tanh(float x) {      // JAX approximate=True
  float z = 0.7978845608028654f * (x + 0.044715f * x * x * x);
  float e = __expf(2.0f * z);
  return 0.5f * x * (1.0f + (1.0f - 2.0f / (e + 1.0f)));
}
__device__ __forceinline__ void gload_lds16(const void* g, void* l) {
  // async global->LDS, 16B/lane; global addr per-lane, LDS dst wave-uniform+lane*16
  __builtin_amdgcn_global_load_lds(
      (__attribute__((address_space(1))) void*)(void*)g,
      (__attribute__((address_space(3))) void*)l, 16, 0, 0);
}

// ---------- x: fp32 -> bf16, token order (fallback path only) ----------
__global__ __launch_bounds__(256) void convert_bf16(const float* __restrict__ in,
                                                    u16* __restrict__ out) {
  const int i = (blockIdx.x * 256 + threadIdx.x) * 4;
  float4 v = *(const float4*)(in + i);
  ushort4 o;
  o.x = f2b(v.x); o.y = f2b(v.y); o.z = f2b(v.z); o.w = f2b(v.w);
  *(ushort4*)(out + i) = o;
}

// ---------- transpose + convert (batched over z):  [z][K][N] f32 -> [z][N][K] bf16 ----------
__global__ __launch_bounds__(256) void transpose_convert(const float* __restrict__ in,
                                                         u16* __restrict__ out,
                                                         int K, int N) {
  __shared__ u16 tile[32][33];
  const int z = blockIdx.z;
  const int k0 = blockIdx.y * 32, n0 = blockIdx.x * 32;
  const int tx = threadIdx.x & 31, ty = threadIdx.x >> 5;   // 32 x 8
  const float* src = in + (size_t)z * K * N;
  u16* dst = out + (size_t)z * N * K;
#pragma unroll
  for (int i = 0; i < 4; ++i)
    tile[ty + i * 8][tx] = f2b(src[(size_t)(k0 + ty + i * 8) * N + n0 + tx]);
  __syncthreads();
#pragma unroll
  for (int i = 0; i < 4; ++i)
    dst[(size_t)(n0 + ty + i * 8) * K + k0 + tx] = tile[tx][ty + i * 8];
}

// ---------- router: fp64 logits, softmax, top-2 (tie -> lower index) ----------
__global__ __launch_bounds__(256) void router_kernel(const float* __restrict__ x,
                                                     const float* __restrict__ wr,
                                                     int T, int* __restrict__ experts,
                                                     float* __restrict__ weights) {
  const int wave = threadIdx.x >> 6, lane = threadIdx.x & 63;
  const int t = blockIdx.x * 4 + wave;
  if (t >= T) return;
  const float* xr = x + (size_t)t * HS;
  double acc[8] = {0, 0, 0, 0, 0, 0, 0, 0};
#pragma unroll
  for (int i = 0; i < HS / 64; ++i) {
    const int hrow = i * 64 + lane;
    double xv = (double)xr[hrow];
    float4 w0 = *(const float4*)(wr + hrow * 8);
    float4 w1 = *(const float4*)(wr + hrow * 8 + 4);
    acc[0] += xv * (double)w0.x; acc[1] += xv * (double)w0.y;
    acc[2] += xv * (double)w0.z; acc[3] += xv * (double)w0.w;
    acc[4] += xv * (double)w1.x; acc[5] += xv * (double)w1.y;
    acc[6] += xv * (double)w1.z; acc[7] += xv * (double)w1.w;
  }
#pragma unroll
  for (int e = 0; e < 8; ++e) {
    double v = acc[e];
#pragma unroll
    for (int off = 32; off > 0; off >>= 1) v += __shfl_xor(v, off, 64);
    acc[e] = v;
  }
  if (lane == 0) {
    double m = acc[0];
#pragma unroll
    for (int e = 1; e < 8; ++e) m = acc[e] > m ? acc[e] : m;
    double s[8], sum = 0.0;
#pragma unroll
    for (int e = 0; e < 8; ++e) { s[e] = exp(acc[e] - m); sum += s[e]; }
    double inv = 1.0 / sum;
    int e1 = 0; double l1 = acc[0];
#pragma unroll
    for (int e = 1; e < 8; ++e) if (acc[e] > l1) { l1 = acc[e]; e1 = e; }
    int e2 = -1; double l2 = -1e300;
#pragma unroll
    for (int e = 0; e < 8; ++e) if (e != e1 && acc[e] > l2) { l2 = acc[e]; e2 = e; }
    experts[2 * t] = e1;  experts[2 * t + 1] = e2;
    weights[2 * t] = (float)(s[e1] * inv);
    weights[2 * t + 1] = (float)(s[e2] * inv);
  }
}

// ---------- per-wave expert histogram + in-wave stable rank ----------
__global__ __launch_bounds__(256) void hist_kernel(const int* __restrict__ experts,
                                                   int* __restrict__ hist,
                                                   unsigned char* __restrict__ lrank) {
  const int n = blockIdx.x * 256 + threadIdx.x;
  const int lane = threadIdx.x & 63;
  const int wid = n >> 6;
  const int e = experts[n];
  int rank = 0;
#pragma unroll
  for (int ev = 0; ev < 8; ++ev) {
    unsigned long long m = __ballot(e == ev);
    if (lane == ev) hist[wid * 8 + ev] = __popcll(m);
    if (e == ev) rank = __popcll(m & ((1ull << lane) - 1ull));
  }
  lrank[n] = (unsigned char)rank;
}

// ---------- single-block scan: chunk-EXCLUSIVE prefix per expert ----------
__global__ __launch_bounds__(512) void scan_kernel(const int* __restrict__ hist,
                                                   int* __restrict__ chunkBase) {
  __shared__ int s[512];
  const int tid = threadIdx.x;     // 512 == nChunks
  for (int e = 0; e < 8; ++e) {
    int v = hist[tid * 8 + e];
    s[tid] = v;
    __syncthreads();
    for (int off = 1; off < 512; off <<= 1) {
      int add = (tid >= off) ? s[tid - off] : 0;
      __syncthreads();
      s[tid] += add;
      __syncthreads();
    }
    chunkBase[tid * 8 + e] = s[tid] - v;   // exclusive, within-expert offset
    __syncthreads();
  }
}

// ---------- slot map init ----------
__global__ __launch_bounds__(256) void slot_init(int* __restrict__ rowtok,
                                                 float* __restrict__ roww) {
  const int i = blockIdx.x * 256 + threadIdx.x;
  rowtok[i] = -1;
  roww[i] = 0.0f;
}

// ---------- gather: fill rowtok/roww; optionally write xb[slot] = bf16(x[token]) ----------
__global__ __launch_bounds__(256) void gather_kernel(const float* __restrict__ x,
                                                     const int* __restrict__ experts,
                                                     const unsigned char* __restrict__ lrank,
                                                     const int* __restrict__ chunkBase,
                                                     const float* __restrict__ weights,
                                                     int capacity, int* __restrict__ rowtok,
                                                     float* __restrict__ roww,
                                                     u16* __restrict__ xb) {
  const int wave = threadIdx.x >> 6, lane = threadIdx.x & 63;
  const int n = blockIdx.x * 4 + wave;           // one wave per assignment
  const int e = experts[n];
  const int off = chunkBase[(n >> 6) * 8 + e] + (int)lrank[n];
  if (off >= capacity) return;
  const int slot = e * capacity + off;
  if (lane == 0) { rowtok[slot] = n >> 1; roww[slot] = weights[n]; }
  if (xb == nullptr) return;
  const float* src = x + (size_t)(n >> 1) * HS;
  u16* dst = xb + (size_t)slot * HS;
#pragma unroll
  for (int i = 0; i < 4; ++i) {
    float4 v = *(const float4*)(src + i * 256 + lane * 4);
    ushort4 o;
    o.x = f2b(v.x); o.y = f2b(v.y); o.z = f2b(v.z); o.w = f2b(v.w);
    *(ushort4*)(dst + i * 256 + lane * 4) = o;
  }
}

// ---------- bias broadcast into out ----------
__global__ __launch_bounds__(256) void bias_init(const float* __restrict__ bias,
                                                 float* __restrict__ out) {
  const int c = threadIdx.x * 4;
  *(float4*)(out + (size_t)blockIdx.x * HS + c) = *(const float4*)(bias + c);
}

// ---------- m97-style bf16 GEMM, batched over blockIdx.z ----------
// A [z][M][K] (or gathered rows via rowtok if GATHER_A), Bt [z][Nn][K], bf16.
// SCATTER: epilogue atomically adds roww*acc into out[rowtok[row]] (fp32);
// else writes bf16 tile (optional GELU) to Cout [z][M][Nn].
template <bool GELU, bool GATHER_A, bool SCATTER>
__global__ __launch_bounds__(256) void gemm_moe(const u16* __restrict__ A,
                                                const u16* __restrict__ Bt,
                                                u16* __restrict__ Cout,
                                                float* __restrict__ out,
                                                const int* __restrict__ rowtok,
                                                const float* __restrict__ roww,
                                                int rtStride, int M, int Nn, int K) {
  const int z = blockIdx.z;
  const int bm = blockIdx.y, bn = blockIdx.x;
  if (!GATHER_A) A += (size_t)z * M * K;
  Bt += (size_t)z * Nn * K;
  rowtok += (size_t)z * rtStride;
  roww += (size_t)z * rtStride;
  const u16* Bb = Bt + (size_t)bn * 128 * K;
  __shared__ u16 As[128 * 32];   // [m][k]
  __shared__ u16 Bs[128 * 32];   // [n][k]
  const int tid = threadIdx.x;
  const int lane = tid & 63, wave = tid >> 6;
  const int wm = (wave >> 1) * 64, wn = (wave & 1) * 64;   // 2x2 waves over 128x128
  const int lrow = lane & 15, quad = lane >> 4;

  f32x4 acc[4][4] = {};

  const int srow = tid >> 2;                // staging row 0..63 (+64 second call)
  const int skoff = (tid & 3) * 8;          // k element offset
  u16* lA = As + tid * 8;                   // byte offset tid*16: lane-contig per wave
  u16* lB = Bs + tid * 8;

  const u16 *ga0, *ga1;
  if (GATHER_A) {
    int t0 = rowtok[bm * 128 + srow];      if (t0 < 0) t0 = 0;
    int t1 = rowtok[bm * 128 + srow + 64]; if (t1 < 0) t1 = 0;
    ga0 = A + (size_t)t0 * K + skoff;
    ga1 = A + (size_t)t1 * K + skoff;
  } else {
    ga0 = A + (size_t)(bm * 128 + srow) * K + skoff;
    ga1 = ga0 + (size_t)64 * K;
  }
  const u16* gb0 = Bb + (size_t)srow * K + skoff;
  const u16* gb1 = gb0 + (size_t)64 * K;

  for (int k0 = 0; k0 < K; k0 += 32) {
    gload_lds16(ga0 + k0, lA);
    gload_lds16(ga1 + k0, lA + 2048);
    gload_lds16(gb0 + k0, lB);
    gload_lds16(gb1 + k0, lB + 2048);
    __syncthreads();
    bf16x8 af[4], bfr[4];
#pragma unroll
    for (int i = 0; i < 4; ++i) {
      af[i]  = *(const bf16x8*)(As + (wm + i * 16 + lrow) * 32 + quad * 8);
      bfr[i] = *(const bf16x8*)(Bs + (wn + i * 16 + lrow) * 32 + quad * 8);
    }
#pragma unroll
    for (int i = 0; i < 4; ++i)
#pragma unroll
      for (int j = 0; j < 4; ++j)
        acc[i][j] = __builtin_amdgcn_mfma_f32_16x16x32_bf16(af[i], bfr[j], acc[i][j], 0, 0, 0);
    __syncthreads();
  }

  // C/D layout: col=lane&15, row=quad*4+reg (m89-verified)
  if (!SCATTER) {
    u16* Cb = Cout + (size_t)z * M * Nn + (size_t)(bm * 128 + wm) * Nn + bn * 128 + wn;
#pragma unroll
    for (int i = 0; i < 4; ++i)
#pragma unroll
      for (int j = 0; j < 4; ++j)
#pragma unroll
        for (int r = 0; r < 4; ++r) {
          float v = acc[i][j][r];
          if (GELU) v = gelu_tanh(v);
          Cb[(size_t)(i * 16 + quad * 4 + r) * Nn + j * 16 + lrow] = f2b(v);
        }
  } else {
#pragma unroll
    for (int i = 0; i < 4; ++i)
#pragma unroll
      for (int r = 0; r < 4; ++r) {
        const int row = bm * 128 + wm + i * 16 + quad * 4 + r;
        const int tok = rowtok[row];
        const float w = roww[row];
        if (tok >= 0) {
          float* op = out + (size_t)tok * HS + bn * 128 + wn + lrow;
#pragma unroll
          for (int j = 0; j < 4; ++j)
            atomicAdd(op + j * 16, w * acc[i][j][r]);
        }
      }
  }
}

extern "C" void kernel_launch(void* const* d_in, const int* in_sizes, int n_in,
                              void* d_out, int out_size, void* d_ws, size_t ws_size,
                              hipStream_t stream) {
  const float* x    = (const float*)d_in[0];
  const float* wr   = (const float*)d_in[1];
  const float* w1   = (const float*)d_in[2];
  const float* w2   = (const float*)d_in[3];
  const float* bias = (const float*)d_in[4];
  float* out = (float*)d_out;

  const int T = in_sizes[0] / HS;          // 16384
  const int N = T * 2;                     // 32768 assignments
  const int capacity = N / NEXP;           // 4096
  const int nChunks = N / 64;              // 512

  // ---- small workspace ----
  char* ws = (char*)d_ws;
  int* experts = (int*)ws;                   ws += (size_t)N * 4;
  float* weights = (float*)ws;               ws += (size_t)N * 4;
  unsigned char* lrank = (unsigned char*)ws; ws += (size_t)N;
  int* hist = (int*)ws;                      ws += (size_t)nChunks * 8 * 4;
  int* chunkBase = (int*)ws;                 ws += (size_t)nChunks * 8 * 4;
  int* rowtok = (int*)ws;                    ws += (size_t)NEXP * capacity * 4;
  float* roww = (float*)ws;                  ws += (size_t)NEXP * capacity * 4;
  ws = (char*)(((uintptr_t)ws + 255) & ~(uintptr_t)255);
  size_t used = (size_t)(ws - (char*)d_ws);
  size_t avail = ws_size > used ? ws_size - used : 0;

  const size_t xbB  = (size_t)NEXP * capacity * HS * 2;   // 64 MB contiguous xb
  const size_t perE = ((size_t)FFN * HS * 2) * 2 + (size_t)capacity * FFN * 2; // w1t+w2t+h = 48 MB

  // Choose largest expert-group size G (with contiguous xb), else fallback path.
  int G = 0;
  for (int g = NEXP; g >= 1; g >>= 1)
    if (avail >= xbB + (size_t)g * perE) { G = g; break; }

  u16 *xb = nullptr, *xbf = nullptr, *w1t, *w2t, *h;
  if (G > 0) {
    xb  = (u16*)ws;  ws += xbB;
    w1t = (u16*)ws;  ws += (size_t)G * FFN * HS * 2;
    w2t = (u16*)ws;  ws += (size_t)G * HS * FFN * 2;
    h   = (u16*)ws;  ws += (size_t)G * capacity * FFN * 2;
  } else {
    // fallback (known-fits 81 MB): token-order bf16 x, gathered staging, G=1
    G = 1;
    xbf = (u16*)ws;  ws += (size_t)T * HS * 2;
    w1t = (u16*)ws;  ws += (size_t)FFN * HS * 2;
    w2t = (u16*)ws;  ws += (size_t)HS * FFN * 2;
    h   = (u16*)ws;  ws += (size_t)capacity * FFN * 2;
    if ((size_t)(ws - (char*)d_ws) > ws_size) return;
    convert_bf16<<<T * HS / 1024, 256, 0, stream>>>(x, xbf);
  }

  // router + stable binning + slot maps (+ contiguous gather if xb)
  router_kernel<<<T / 4, 256, 0, stream>>>(x, wr, T, experts, weights);
  hist_kernel<<<N / 256, 256, 0, stream>>>(experts, hist, lrank);
  scan_kernel<<<1, 512, 0, stream>>>(hist, chunkBase);
  slot_init<<<NEXP * capacity / 256, 256, 0, stream>>>(rowtok, roww);
  gather_kernel<<<N / 4, 256, 0, stream>>>(x, experts, lrank, chunkBase, weights,
                                           capacity, rowtok, roww, xb);
  // out = bias; GEMM2 scatter-adds on top
  bias_init<<<T, 256, 0, stream>>>(bias, out);

  for (int e0 = 0; e0 < NEXP; e0 += G) {
    const float* w1_g = w1 + (size_t)e0 * HS * FFN;
    const float* w2_g = w2 + (size_t)e0 * FFN * HS;
    const int* rt_g = rowtok + e0 * capacity;
    const float* rw_g = roww + e0 * capacity;
    transpose_convert<<<dim3(FFN / 32, HS / 32, G), 256, 0, stream>>>(w1_g, w1t, HS, FFN);
    transpose_convert<<<dim3(HS / 32, FFN / 32, G), 256, 0, stream>>>(w2_g, w2t, FFN, HS);
    if (xb != nullptr) {
      gemm_moe<true, false, false><<<dim3(FFN / 128, capacity / 128, G), 256, 0, stream>>>(
          xb + (size_t)e0 * capacity * HS, w1t, h, nullptr, rt_g, rw_g,
          capacity, capacity, FFN, HS);
    } else {
      gemm_moe<true, true, false><<<dim3(FFN / 128, capacity / 128, G), 256, 0, stream>>>(
          xbf, w1t, h, nullptr, rt_g, rw_g, capacity, capacity, FFN, HS);
    }
    gemm_moe<false, false, true><<<dim3(HS / 128, capacity / 128, G), 256, 0, stream>>>(
        h, w2t, nullptr, out, rt_g, rw_g, capacity, capacity, HS, FFN);
  }
}